// Round 4
// baseline (239.467 us; speedup 1.0000x reference)
//
#include <hip/hip_runtime.h>
#include <hip/hip_bf16.h>

#define D 1024      // in_features
#define E 64        // num experts
#define TPB 256     // threads per block (4 waves)
#define TOKS 64     // tokens per block (16 per wave)
#define KC 64       // k per chunk (2 MFMA k-steps)
#define NCHUNK (D / KC)   // 16

typedef __attribute__((ext_vector_type(8))) short bf16x8;
typedef __attribute__((ext_vector_type(4))) float f32x4;
typedef __attribute__((ext_vector_type(4))) int i32x4;
typedef __attribute__((ext_vector_type(4))) unsigned short u16x4;

__device__ __forceinline__ unsigned short bf16_rne(float f) {
    unsigned u = __builtin_bit_cast(unsigned, f);
    u += 0x7fffu + ((u >> 16) & 1u);
    return (unsigned short)(u >> 16);
}
__device__ __forceinline__ float bf16_as_f(unsigned short h) {
    unsigned u = ((unsigned)h) << 16;
    return __builtin_bit_cast(float, u);
}
__device__ __forceinline__ void split_hi_lo(float v, unsigned short& h, unsigned short& l) {
    h = bf16_rne(v);
    l = bf16_rne(v - bf16_as_f(h));
}

// ---- pre-kernel: split W (fp32) into hi/lo bf16 planes in d_ws (runs every call) ----
__global__ __launch_bounds__(256) void wsplit_kernel(const float* __restrict__ W,
        unsigned short* __restrict__ whi, unsigned short* __restrict__ wlo) {
    int g = blockIdx.x * 256 + threadIdx.x;     // 16384 threads x 4 elems = 64K
    f32x4 w = *(const f32x4*)(W + (size_t)g * 4);
    u16x4 h, l;
#pragma unroll
    for (int j = 0; j < 4; ++j) {
        unsigned short hh, ll;
        split_hi_lo(w[j], hh, ll);
        h[j] = hh; l[j] = ll;
    }
    *(u16x4*)(whi + (size_t)g * 4) = h;
    *(u16x4*)(wlo + (size_t)g * 4) = l;
}

// Barrier-free K-loop: B-fragments straight from global (L1/L2-resident bf16 W
// planes), A prefetched one chunk ahead in registers. No LDS until epilogue.
__global__ __launch_bounds__(TPB, 2) void router_kernel(
        const float* __restrict__ x,
        const unsigned short* __restrict__ whi,
        const unsigned short* __restrict__ wlo,
        const float* __restrict__ bias,
        float* __restrict__ out, int T) {
    __shared__ float ls[TOKS][E + 1];   // epilogue logits only

    const int tid  = threadIdx.x;
    const int lane = tid & 63;
    const int wid  = tid >> 6;     // wave id 0..3 -> 16-token strip
    const int n    = lane & 15;    // MFMA m/n index within tile
    const int q    = lane >> 4;    // MFMA quad -> k offset q*8
    const int t0   = blockIdx.x * TOKS;

    // C init = bias broadcast (C/D layout: col = lane&15 = expert nt*16+n)
    f32x4 acc[4];
#pragma unroll
    for (int nt = 0; nt < 4; ++nt) {
        float bv = bias[nt * 16 + n];
        acc[nt] = (f32x4){bv, bv, bv, bv};
    }

    // A source: this lane reads 8 consecutive fp32 per k-step, MFMA lane order
    const float* arow = x + (size_t)(t0 + wid * 16 + n) * D + q * 8;
    // B source: lane (n,q) element offset within each plane, per nt tile
    size_t brow[4];
#pragma unroll
    for (int nt = 0; nt < 4; ++nt) brow[nt] = (size_t)(nt * 16 + n) * D + q * 8;

    i32x4 breg[4][2][2];    // [nt][s][plane]
    f32x4 aregA[4], aregB[4];

    auto load_b = [&](int c) {
#pragma unroll
        for (int nt = 0; nt < 4; ++nt)
#pragma unroll
            for (int s = 0; s < 2; ++s) {
                breg[nt][s][0] = *(const i32x4*)(whi + brow[nt] + c * KC + s * 32);
                breg[nt][s][1] = *(const i32x4*)(wlo + brow[nt] + c * KC + s * 32);
            }
    };
    auto load_a = [&](int c, f32x4* ar) {
#pragma unroll
        for (int s = 0; s < 2; ++s) {
            ar[2 * s]     = *(const f32x4*)(arow + c * KC + s * 32);
            ar[2 * s + 1] = *(const f32x4*)(arow + c * KC + s * 32 + 4);
        }
    };

    load_a(0, aregA);

    for (int kc = 0; kc < NCHUNK; ++kc) {
        load_b(kc);                          // B first: waitcnt on B won't drain A
        int kn = (kc + 1) & (NCHUNK - 1);    // branchless wrap; last iter harmless
        load_a(kn, aregB);                   // HBM prefetch, outstanding across chunk

        // ---- compute: 2 MFMA k-steps (round-1 verified RNE split + 3-MFMA) ----
#pragma unroll
        for (int s = 0; s < 2; ++s) {
            unsigned short ah[8], al[8];
#pragma unroll
            for (int j = 0; j < 4; ++j) {
                split_hi_lo(aregA[2 * s][j],     ah[j],     al[j]);
                split_hi_lo(aregA[2 * s + 1][j], ah[4 + j], al[4 + j]);
            }
            bf16x8 ahv, alv;
#pragma unroll
            for (int j = 0; j < 8; ++j) { ahv[j] = (short)ah[j]; alv[j] = (short)al[j]; }
#pragma unroll
            for (int nt = 0; nt < 4; ++nt) {
                const bf16x8 bh = __builtin_bit_cast(bf16x8, breg[nt][s][0]);
                const bf16x8 bl = __builtin_bit_cast(bf16x8, breg[nt][s][1]);
                acc[nt] = __builtin_amdgcn_mfma_f32_16x16x32_bf16(ahv, bh, acc[nt], 0, 0, 0);
                acc[nt] = __builtin_amdgcn_mfma_f32_16x16x32_bf16(alv, bh, acc[nt], 0, 0, 0);
                acc[nt] = __builtin_amdgcn_mfma_f32_16x16x32_bf16(ahv, bl, acc[nt], 0, 0, 0);
            }
        }
#pragma unroll
        for (int i = 0; i < 4; ++i) aregA[i] = aregB[i];
    }

    // ---- epilogue: logits to LDS (bias already in acc), per-token softmax+top-2 ----
#pragma unroll
    for (int nt = 0; nt < 4; ++nt) {
#pragma unroll
        for (int r = 0; r < 4; ++r) {
            // C/D layout: col = lane&15, row = (lane>>4)*4 + reg
            ls[wid * 16 + q * 4 + r][nt * 16 + n] = acc[nt][r];
        }
    }
    __syncthreads();

    if (tid < TOKS) {
        float m1 = -3.4e38f, m2 = -3.4e38f;
        int i1 = 0, i2 = 0;
        for (int e = 0; e < E; ++e) {
            float v = ls[tid][e];
            if (v > m1) { m2 = m1; i2 = i1; m1 = v; i1 = e; }
            else if (v > m2) { m2 = v; i2 = e; }
        }
        float Z = 0.f;
        for (int e = 0; e < E; ++e) Z += __expf(ls[tid][e] - m1);
        float inv = 1.f / Z;
        int gt = t0 + tid;
        out[(size_t)gt * 2]     = inv;                 // exp(m1-m1)/Z
        out[(size_t)gt * 2 + 1] = __expf(m2 - m1) * inv;
        float* oi = out + (size_t)T * 2;
        oi[(size_t)gt * 2]     = (float)i1;            // indices stored as float values
        oi[(size_t)gt * 2 + 1] = (float)i2;
    }
}

extern "C" void kernel_launch(void* const* d_in, const int* in_sizes, int n_in,
                              void* d_out, int out_size, void* d_ws, size_t ws_size,
                              hipStream_t stream) {
    const float* x = (const float*)d_in[0];
    const float* W = (const float*)d_in[1];
    const float* b = (const float*)d_in[2];
    float* out = (float*)d_out;
    unsigned short* whi = (unsigned short*)d_ws;
    unsigned short* wlo = whi + (size_t)E * D;
    int T = in_sizes[0] / D;                  // 32768 tokens
    hipLaunchKernelGGL(wsplit_kernel, dim3((E * D) / 1024), dim3(256), 0, stream,
                       W, whi, wlo);
    hipLaunchKernelGGL(router_kernel, dim3(T / TOKS), dim3(TPB), 0, stream,
                       x, whi, wlo, b, out, T);
}

// Round 5
// 208.280 us; speedup vs baseline: 1.1497x; 1.1497x over previous
//
#include <hip/hip_runtime.h>
#include <hip/hip_bf16.h>

#define D 1024      // in_features
#define E 64        // num experts
#define TPB 256     // threads per block (4 waves)
#define TOKS 64     // tokens per block (16 per wave)
#define KC 64       // k per staged chunk (2 MFMA k-steps)
#define NCHUNK (D / KC)   // 16
#define BROW 72     // padded bf16 row (144 B, 16B-aligned)
#define APAD 68     // padded fp32 A row (272 B, 16B-aligned, bank-spread)

typedef __attribute__((ext_vector_type(8))) short bf16x8;
typedef __attribute__((ext_vector_type(4))) float f32x4;
typedef __attribute__((ext_vector_type(4))) int i32x4;
typedef __attribute__((ext_vector_type(4))) unsigned short u16x4;

__device__ __forceinline__ unsigned short bf16_rne(float f) {
    unsigned u = __builtin_bit_cast(unsigned, f);
    u += 0x7fffu + ((u >> 16) & 1u);
    return (unsigned short)(u >> 16);
}
__device__ __forceinline__ float bf16_as_f(unsigned short h) {
    unsigned u = ((unsigned)h) << 16;
    return __builtin_bit_cast(float, u);
}
__device__ __forceinline__ void split_hi_lo(float v, unsigned short& h, unsigned short& l) {
    h = bf16_rne(v);
    l = bf16_rne(v - bf16_as_f(h));
}

// ---- pre-kernel: split W into hi/lo bf16 planes, CHUNK-MAJOR layout ----
// plane[c][e][kk] (shorts): chunk c = 8 KB contiguous -> staging loads stream
__global__ __launch_bounds__(256) void wsplit_kernel(const float* __restrict__ W,
        unsigned short* __restrict__ whi, unsigned short* __restrict__ wlo) {
    int g = blockIdx.x * 256 + threadIdx.x;   // 16384 threads x 4 elems
    int e = g >> 8;                           // row (1024 floats/row, 4/thread)
    int k = (g & 255) * 4;                    // col base (same chunk for all 4)
    int c = k >> 6, kk = k & 63;
    f32x4 w = *(const f32x4*)(W + (size_t)g * 4);
    u16x4 h, l;
#pragma unroll
    for (int j = 0; j < 4; ++j) {
        unsigned short hh, ll;
        split_hi_lo(w[j], hh, ll);
        h[j] = hh; l[j] = ll;
    }
    size_t o = (size_t)c * (E * KC) + e * KC + kk;   // shorts
    *(u16x4*)(whi + o) = h;
    *(u16x4*)(wlo + o) = l;
}

__global__ __launch_bounds__(TPB, 2) void router_kernel(
        const float* __restrict__ x,
        const unsigned short* __restrict__ whi,
        const unsigned short* __restrict__ wlo,
        const float* __restrict__ bias,
        float* __restrict__ out, int T) {
    // W: double-buffered padded chunk; A: per-wave padded staging (union w/ epilogue)
    __shared__ __align__(16) unsigned short wb[2][2][E][BROW];   // 36864 B
    __shared__ __align__(16) union SMA {
        float Ax[4][16][APAD];    // per-wave A chunk staging (17408 B)
        float ls[TOKS][E + 1];    // epilogue logits (16640 B)
    } sma;

    const int tid  = threadIdx.x;
    const int lane = tid & 63;
    const int wid  = tid >> 6;     // wave -> 16-token strip
    const int n    = lane & 15;    // MFMA m/n index
    const int q    = lane >> 4;    // MFMA quad -> k offset q*8
    const int t0   = blockIdx.x * TOKS;

    // C init = bias broadcast (verified r4 path)
    f32x4 acc[4];
#pragma unroll
    for (int nt = 0; nt < 4; ++nt) {
        float bv = bias[nt * 16 + n];
        acc[nt] = (f32x4){bv, bv, bv, bv};
    }

    // ---- contiguous A loads: inst i covers rows 4i..4i+3, 256B slice each ----
    const float* abase = x + (size_t)(t0 + wid * 16) * D;
    const int arow_i = (lane >> 4);          // row within inst group
    const int acol   = (lane & 15) * 4;      // float col within 64-float slice
    f32x4 aregA[4], aregB[4];
    auto load_a = [&](int c, f32x4* ar) {
#pragma unroll
        for (int i = 0; i < 4; ++i)
            ar[i] = *(const f32x4*)(abase + (i * 4 + arow_i) * D + c * KC + acol);
    };
    auto write_a = [&](const f32x4* ar) {
#pragma unroll
        for (int i = 0; i < 4; ++i)
            *(f32x4*)&sma.Ax[wid][i * 4 + arow_i][acol] = ar[i];
    };

    // ---- contiguous W staging from chunk-major planes ----
    i32x4 wreg[4];
    auto load_w = [&](int c) {
#pragma unroll
        for (int r = 0; r < 4; ++r) {
            int idx = r * TPB + tid;          // 0..1023
            const unsigned short* src = (idx >> 9) ? wlo : whi;
            wreg[r] = *(const i32x4*)(src + (size_t)c * (E * KC) + (idx & 511) * 8);
        }
    };
    auto store_w = [&](int buf) {
#pragma unroll
        for (int r = 0; r < 4; ++r) {
            int idx = r * TPB + tid;
            int pl = idx >> 9, j = idx & 511, e = j >> 3, blk = j & 7;
            *(i32x4*)&wb[buf][pl][e][blk * 8] = wreg[r];
        }
    };

    // ---- compute on chunk in wb[buf] + this wave's sma.Ax ----
    auto kstep = [&](int buf) {
#pragma unroll
        for (int s = 0; s < 2; ++s) {
            const float* ap = &sma.Ax[wid][n][s * 32 + q * 8];
            f32x4 a0 = ((const f32x4*)ap)[0];
            f32x4 a1 = ((const f32x4*)ap)[1];
            unsigned short ah[8], al[8];
#pragma unroll
            for (int j = 0; j < 4; ++j) {
                split_hi_lo(a0[j], ah[j],     al[j]);
                split_hi_lo(a1[j], ah[4 + j], al[4 + j]);
            }
            bf16x8 ahv, alv;
#pragma unroll
            for (int j = 0; j < 8; ++j) { ahv[j] = (short)ah[j]; alv[j] = (short)al[j]; }
#pragma unroll
            for (int nt = 0; nt < 4; ++nt) {
                const bf16x8 bh = *(const bf16x8*)&wb[buf][0][nt * 16 + n][s * 32 + q * 8];
                const bf16x8 bl = *(const bf16x8*)&wb[buf][1][nt * 16 + n][s * 32 + q * 8];
                acc[nt] = __builtin_amdgcn_mfma_f32_16x16x32_bf16(ahv, bh, acc[nt], 0, 0, 0);
                acc[nt] = __builtin_amdgcn_mfma_f32_16x16x32_bf16(alv, bh, acc[nt], 0, 0, 0);
                acc[nt] = __builtin_amdgcn_mfma_f32_16x16x32_bf16(ahv, bl, acc[nt], 0, 0, 0);
            }
        }
    };

    // ---- prologue: stage chunk 0 ----
    load_w(0);
    load_a(0, aregA);
    store_w(0);
    __syncthreads();

    // ---- main loop: ONE barrier per chunk; W double-buffered; A wave-private ----
    for (int kc = 0; kc < NCHUNK; ++kc) {
        const int p = kc & 1;
        const int kn = (kc + 1) & (NCHUNK - 1);   // wrap; last iter harmless
        load_w(kn);                // L2 stream (contiguous)
        load_a(kn, aregB);         // HBM stream (contiguous), in flight over compute
        write_a(aregA);            // wave-private LDS, no barrier needed
        kstep(p);                  // covers load_w's L2 latency
        store_w(p ^ 1);            // vmcnt(wreg) satisfied by now
#pragma unroll
        for (int i = 0; i < 4; ++i) aregA[i] = aregB[i];
        __syncthreads();
    }

    // ---- epilogue: logits to LDS (bias already in acc), softmax + top-2 ----
#pragma unroll
    for (int nt = 0; nt < 4; ++nt) {
#pragma unroll
        for (int r = 0; r < 4; ++r) {
            // C/D layout: col = lane&15, row = (lane>>4)*4 + reg
            sma.ls[wid * 16 + q * 4 + r][nt * 16 + n] = acc[nt][r];
        }
    }
    __syncthreads();

    if (tid < TOKS) {
        float m1 = -3.4e38f, m2 = -3.4e38f;
        int i1 = 0, i2 = 0;
        for (int e = 0; e < E; ++e) {
            float v = sma.ls[tid][e];
            if (v > m1) { m2 = m1; i2 = i1; m1 = v; i1 = e; }
            else if (v > m2) { m2 = v; i2 = e; }
        }
        float Z = 0.f;
        for (int e = 0; e < E; ++e) Z += __expf(sma.ls[tid][e] - m1);
        float inv = 1.f / Z;
        int gt = t0 + tid;
        out[(size_t)gt * 2]     = inv;
        out[(size_t)gt * 2 + 1] = __expf(m2 - m1) * inv;
        float* oi = out + (size_t)T * 2;
        oi[(size_t)gt * 2]     = (float)i1;   // indices stored as float values
        oi[(size_t)gt * 2 + 1] = (float)i2;
    }
}

extern "C" void kernel_launch(void* const* d_in, const int* in_sizes, int n_in,
                              void* d_out, int out_size, void* d_ws, size_t ws_size,
                              hipStream_t stream) {
    const float* x = (const float*)d_in[0];
    const float* W = (const float*)d_in[1];
    const float* b = (const float*)d_in[2];
    float* out = (float*)d_out;
    unsigned short* whi = (unsigned short*)d_ws;
    unsigned short* wlo = whi + (size_t)E * D;
    int T = in_sizes[0] / D;                  // 32768 tokens
    hipLaunchKernelGGL(wsplit_kernel, dim3((E * D) / 1024), dim3(256), 0, stream,
                       W, whi, wlo);
    hipLaunchKernelGGL(router_kernel, dim3(T / TOKS), dim3(TPB), 0, stream,
                       x, whi, wlo, b, out, T);
}